// Round 1
// baseline (1794.631 us; speedup 1.0000x reference)
//
#include <hip/hip_runtime.h>
#include <math.h>

namespace {
constexpr int N_TOK  = 8192;
constexpr int H      = 32;
constexpr int G      = 8;
constexpr int D      = 128;
constexpr int GROUPS = 4;   // H / G
constexpr int R      = 4;
constexpr int NOPE   = 960; // nope_in
} // namespace

// One block per token. 320 threads = 5 waves (4 q-groups + 1 k-wave).
__global__ __launch_bounds__(320)
void indexer_kernel(const float* __restrict__ q,       // [N,32,128]
                    const float* __restrict__ k,       // [N,8,128]
                    const float* __restrict__ v,       // [N,8,128]
                    const float* __restrict__ q_orig,  // [N,32,128]
                    const float* __restrict__ k_orig,  // [N,8,128]
                    const float* __restrict__ widx,    // [32,16,16]
                    const float* __restrict__ wn,      // [64,960]
                    const float* __restrict__ vt,      // [32,128,4]
                    float* __restrict__ out_iq,        // [N,4,128]
                    float* __restrict__ out_ik,        // [N,128]
                    float* __restrict__ out_w)         // [N,4]
{
    __shared__ __align__(16) float s_nope[5][NOPE];   // 4 q-groups + k
    __shared__ float s_wsq[128];

    const int n   = blockIdx.x;
    const int tid = threadIdx.x;

    // ---------------- Phase A: fold + band projection ----------------
    // Band task: (j, part, B). j = q-group (waves 0..3) or k (wave 4).
    // part: 0 = real half (d' in [0,64)), 1 = imag half.
    // fold: folded[B][c] = t[g, dp] with g=c%8, dp=4*(B%16)+2*(c/8)+(B/16)+part*64
    // proj: P[B][o] = sum_c folded[B][c] * widx[B][c][o]
    //   o==0    -> rope output (from q / k, post-RoPE)
    //   o=1..15 -> nope vector (from q_orig / k_orig), elem B*15+(o-1) (+480 imag)
    {
        const bool is_q = (tid < 256);
        const int  j    = is_q ? (tid >> 6) : 0;
        const int  rem  = is_q ? (tid & 63) : (tid - 256);
        const int  part = rem >> 5;
        const int  B    = rem & 31;

        float acc_rope = 0.f;
        float acc_nope[15];
#pragma unroll
        for (int o = 0; o < 15; ++o) acc_nope[o] = 0.f;

        const float* wB       = widx + B * 256;          // [c][o] 16x16
        const float* rope_src = is_q ? q      : k;
        const float* nope_src = is_q ? q_orig : k_orig;
        const int    base     = is_q ? (n * H * D) : (n * G * D);

#pragma unroll
        for (int c = 0; c < 16; ++c) {
            const int g    = c & 7;
            const int dp   = 4 * (B & 15) + 2 * (c >> 3) + (B >> 4) + part * 64;
            const int head = is_q ? (g * GROUPS + j) : g;
            const int off  = base + head * D + dp;
            const float a_r = rope_src[off];
            const float a_n = nope_src[off];
            const float* wc = wB + c * 16;
            acc_rope += a_r * wc[0];
#pragma unroll
            for (int o = 1; o < 16; ++o)
                acc_nope[o - 1] += a_n * wc[o];
        }

        const int jj = is_q ? j : 4;
        float* dst = &s_nope[jj][part * 480 + B * 15];
#pragma unroll
        for (int o = 0; o < 15; ++o) dst[o] = acc_nope[o];

        if (is_q) out_iq[n * (GROUPS * D) + j * D + part * 32 + B] = acc_rope;
        else      out_ik[n * D + part * 32 + B] = acc_rope;
    }
    __syncthreads();

    // ---------------- Phase B: nope low-rank matvec ----------------
    // y[jj][d2] = sum_i s_nope[jj][i] * wn[d2][i];  jj = wave (0..3 q, 4 k)
    {
        const int jj = tid >> 6;
        const int d2 = tid & 63;
        const float4* xr = (const float4*)(&s_nope[jj][0]);
        const float4* wr = (const float4*)(wn + d2 * NOPE);
        float acc = 0.f;
#pragma unroll 5
        for (int i = 0; i < 240; ++i) {
            const float4 x = xr[i];   // wave-uniform broadcast read
            const float4 w = wr[i];   // per-lane row, L1/L2 resident
            acc += x.x * w.x;
            acc += x.y * w.y;
            acc += x.z * w.z;
            acc += x.w * w.w;
        }
        if (jj < 4) out_iq[n * (GROUPS * D) + jj * D + 64 + d2] = acc;
        else        out_ik[n * D + 64 + d2] = acc;
    }

    // ---------------- Phase C: per-head weights from V ----------------
    // w[h][rr] = sum_d v[g][d] * vt[h][d][rr],  h = g*4+j
    // weights[j] = || { w[g*4+j][rr] } ||_2  over g in [0,8), rr in [0,4)
    if (tid < 128) {
        const int h  = tid >> 2;
        const int rr = tid & 3;
        const int g  = h >> 2;
        const float* vrow = v  + n * (G * D) + g * D;
        const float* vtp  = vt + h * (D * R) + rr;
        float acc = 0.f;
#pragma unroll 8
        for (int d = 0; d < D; ++d) acc += vrow[d] * vtp[d * R];
        s_wsq[tid] = acc * acc;
    }
    __syncthreads();
    if (tid < 4) {
        float s = 0.f;
#pragma unroll
        for (int g = 0; g < 8; ++g)
#pragma unroll
            for (int rr = 0; rr < 4; ++rr)
                s += s_wsq[(g * 4 + tid) * 4 + rr];
        out_w[n * GROUPS + tid] = sqrtf(s);
    }
}

extern "C" void kernel_launch(void* const* d_in, const int* in_sizes, int n_in,
                              void* d_out, int out_size, void* d_ws, size_t ws_size,
                              hipStream_t stream) {
    const float* q      = (const float*)d_in[0];
    const float* k      = (const float*)d_in[1];
    const float* v      = (const float*)d_in[2];
    const float* q_orig = (const float*)d_in[3];
    const float* k_orig = (const float*)d_in[4];
    const float* widx   = (const float*)d_in[5];
    const float* wn     = (const float*)d_in[6];
    const float* vt     = (const float*)d_in[7];

    float* out_iq = (float*)d_out;
    float* out_ik = out_iq + (size_t)N_TOK * GROUPS * D;  // 4,194,304
    float* out_w  = out_ik + (size_t)N_TOK * D;           // +1,048,576

    hipLaunchKernelGGL(indexer_kernel, dim3(N_TOK), dim3(320), 0, stream,
                       q, k, v, q_orig, k_orig, widx, wn, vt,
                       out_iq, out_ik, out_w);
}

// Round 2
// 474.117 us; speedup vs baseline: 3.7852x; 3.7852x over previous
//
#include <hip/hip_runtime.h>
#include <math.h>

namespace {
constexpr int N_TOK  = 8192;
constexpr int GROUPS = 4;
constexpr int D      = 128;
} // namespace

typedef short v8s __attribute__((ext_vector_type(8)));
typedef float v4f __attribute__((ext_vector_type(4)));

__device__ __forceinline__ short f2bf(float f) {
    union { float f; unsigned u; } x; x.f = f;
    unsigned r = x.u + 0x7FFFu + ((x.u >> 16) & 1u);
    return (short)(r >> 16);
}

// ---------------------------------------------------------------------------
// Build M^T [128 cols][1024 k] bf16 in workspace.
//   k = g*128 + dp (head-in-group g 0..7, dp 0..127)
//   fold algebra: part = dp>>6, dpp = dp&63, B = (dpp&1)*16 + (dpp>>2),
//                 c = g + 8*((dpp>>1)&1)
//   col < 64  (rope, from q/k):      nonzero only at col == part*32+B: widx[B][c][0]
//   col >= 64 (nope, from q_orig/k_orig): d2 = col-64:
//       sum_{o=1..15} widx[B][c][o] * Wn[d2][part*480 + B*15 + (o-1)]
// ---------------------------------------------------------------------------
__global__ __launch_bounds__(256)
void build_MT(const float* __restrict__ widx,  // [32][16][16]
              const float* __restrict__ wn,    // [64][960]
              short* __restrict__ MT)          // [128][1024]
{
    const int idx = blockIdx.x * 256 + threadIdx.x;   // 131072 total
    const int col = idx >> 10;
    const int kk  = idx & 1023;
    const int g   = kk >> 7;
    const int dp  = kk & 127;
    const int part = dp >> 6;
    const int dpp  = dp & 63;
    const int B    = (dpp & 1) * 16 + (dpp >> 2);
    const int c    = g + 8 * ((dpp >> 1) & 1);

    float val;
    if (col < 64) {
        val = (col == part * 32 + B) ? widx[B * 256 + c * 16] : 0.f;
    } else {
        const int d2 = col - 64;
        const float* wrow = wn + d2 * 960 + part * 480 + B * 15;
        const float* wi   = widx + B * 256 + c * 16;
        float s = 0.f;
#pragma unroll
        for (int o = 1; o < 16; ++o) s += wi[o] * wrow[o - 1];
        val = s;
    }
    MT[idx] = f2bf(val);
}

// ---------------------------------------------------------------------------
// Main GEMM: Out[40960][128] = A[40960][1024] x M[1024][128]
// Row r = n*5 + jj (jj 0..3 = q-groups, jj 4 = k). A elements gathered
// directly from q/k (rope cols 0..63) and q_orig/k_orig (nope cols 64..127).
// 64 rows per block (4 waves x 16 rows), full 128-col width per wave.
// mfma_f32_16x16x32_bf16; A frag: lane holds row m=lane&15, k=quad*8+j.
// B frag: lane holds col lane&15, k=quad*8+j -> contiguous bf16x8 from M^T.
// ---------------------------------------------------------------------------
__global__ __launch_bounds__(256)
void gemm_kernel(const float* __restrict__ q,       // [N,32,128]
                 const float* __restrict__ k,       // [N,8,128]
                 const float* __restrict__ q_orig,  // [N,32,128]
                 const float* __restrict__ k_orig,  // [N,8,128]
                 const short* __restrict__ MT,      // [128][1024] bf16
                 float* __restrict__ out_iq,        // [N,4,128]
                 float* __restrict__ out_ik)        // [N,128]
{
    const int lane = threadIdx.x & 63;
    const int wave = threadIdx.x >> 6;
    const int m    = lane & 15;
    const int quad = lane >> 4;
    const int base_row = blockIdx.x * 64 + wave * 16;

    // per-lane A row
    const int row = base_row + m;
    const int n   = row / 5;
    const int jj  = row - n * 5;
    const bool isq = (jj < 4);
    // for q rows: element k=g*128+dp lives at q[n, g*4+jj, dp] -> base + g*512 + dp
    const float* ropep = isq ? (q      + n * 4096 + jj * 128) : (k      + n * 1024);
    const float* nopep = isq ? (q_orig + n * 4096 + jj * 128) : (k_orig + n * 1024);

    const short* bbase = MT + m * 1024;

    v4f acc[8];
#pragma unroll
    for (int t = 0; t < 8; ++t) acc[t] = (v4f){0.f, 0.f, 0.f, 0.f};

#pragma unroll 2
    for (int ks = 0; ks < 32; ++ks) {
        const int kk   = ks * 32 + quad * 8;
        const int offA = isq ? ((kk >> 7) * 512 + (kk & 127)) : kk;
        const float4 r0 = *(const float4*)(ropep + offA);
        const float4 r1 = *(const float4*)(ropep + offA + 4);
        const float4 n0 = *(const float4*)(nopep + offA);
        const float4 n1 = *(const float4*)(nopep + offA + 4);
        v8s ar, an;
        ar[0] = f2bf(r0.x); ar[1] = f2bf(r0.y); ar[2] = f2bf(r0.z); ar[3] = f2bf(r0.w);
        ar[4] = f2bf(r1.x); ar[5] = f2bf(r1.y); ar[6] = f2bf(r1.z); ar[7] = f2bf(r1.w);
        an[0] = f2bf(n0.x); an[1] = f2bf(n0.y); an[2] = f2bf(n0.z); an[3] = f2bf(n0.w);
        an[4] = f2bf(n1.x); an[5] = f2bf(n1.y); an[6] = f2bf(n1.z); an[7] = f2bf(n1.w);

        const short* bp = bbase + kk;
#pragma unroll
        for (int t = 0; t < 8; ++t) {
            const v8s b = *(const v8s*)(bp + t * 16384);  // t*16 cols * 1024
            acc[t] = __builtin_amdgcn_mfma_f32_16x16x32_bf16(
                         (t < 4) ? ar : an, b, acc[t], 0, 0, 0);
        }
    }

    // C/D layout: col = lane&15, row_in_tile = quad*4 + reg
#pragma unroll
    for (int t = 0; t < 8; ++t) {
        const int col = t * 16 + m;
#pragma unroll
        for (int i = 0; i < 4; ++i) {
            const int r2  = base_row + quad * 4 + i;
            const int n2  = r2 / 5;
            const int jj2 = r2 - n2 * 5;
            float* dst = (jj2 < 4) ? (out_iq + n2 * 512 + jj2 * 128)
                                   : (out_ik + n2 * 128);
            dst[col] = acc[t][i];
        }
    }
}

// ---------------------------------------------------------------------------
// Weights: w[n,h,rr] = sum_d v[n,h>>2,d] * vt[h,d,rr];
// weights[n,j] = ||{w[n,g*4+j,rr]}||_2. Two tokens per 256-thread block.
// ---------------------------------------------------------------------------
__global__ __launch_bounds__(256)
void weights_kernel(const float* __restrict__ v,    // [N,8,128]
                    const float* __restrict__ vt,   // [32,128,4]
                    float* __restrict__ out_w)      // [N,4]
{
    __shared__ float s_wsq[2][128];
    const int half = threadIdx.x >> 7;
    const int tid  = threadIdx.x & 127;
    const int tok  = blockIdx.x * 2 + half;
    const int h  = tid >> 2;
    const int rr = tid & 3;
    const int g  = h >> 2;
    const float* vrow = v  + tok * 1024 + g * 128;
    const float* vtp  = vt + h * 512 + rr;
    float acc = 0.f;
#pragma unroll 8
    for (int d = 0; d < 128; ++d) acc += vrow[d] * vtp[d * 4];
    s_wsq[half][tid] = acc * acc;
    __syncthreads();
    if (tid < 4) {
        float s = 0.f;
#pragma unroll
        for (int g2 = 0; g2 < 8; ++g2)
#pragma unroll
            for (int r2 = 0; r2 < 4; ++r2)
                s += s_wsq[half][(g2 * 4 + tid) * 4 + r2];
        out_w[tok * 4 + tid] = sqrtf(s);
    }
}

extern "C" void kernel_launch(void* const* d_in, const int* in_sizes, int n_in,
                              void* d_out, int out_size, void* d_ws, size_t ws_size,
                              hipStream_t stream) {
    const float* q      = (const float*)d_in[0];
    const float* k      = (const float*)d_in[1];
    const float* v      = (const float*)d_in[2];
    const float* q_orig = (const float*)d_in[3];
    const float* k_orig = (const float*)d_in[4];
    const float* widx   = (const float*)d_in[5];
    const float* wn     = (const float*)d_in[6];
    const float* vt     = (const float*)d_in[7];

    float* out_iq = (float*)d_out;
    float* out_ik = out_iq + (size_t)N_TOK * GROUPS * D;  // +4,194,304
    float* out_w  = out_ik + (size_t)N_TOK * D;           // +1,048,576

    short* MT = (short*)d_ws;  // 128*1024 bf16 = 256 KB

    hipLaunchKernelGGL(build_MT, dim3(512), dim3(256), 0, stream, widx, wn, MT);
    hipLaunchKernelGGL(gemm_kernel, dim3(640), dim3(256), 0, stream,
                       q, k, q_orig, k_orig, MT, out_iq, out_ik);
    hipLaunchKernelGGL(weights_kernel, dim3(4096), dim3(256), 0, stream,
                       v, vt, out_w);
}